// Round 15
// baseline (225.046 us; speedup 1.0000x reference)
//
#include <hip/hip_runtime.h>
#include <stdint.h>

typedef unsigned short u16;
typedef unsigned int u32;
typedef __attribute__((ext_vector_type(8))) short bf16x8;      // 8 bf16 (4 VGPRs) MFMA A/B frag
typedef __attribute__((ext_vector_type(4))) float f32x4;       // 16x16 MFMA C/D frag
typedef __attribute__((ext_vector_type(16))) float f32x16;     // 32x32 MFMA C/D frag
typedef __attribute__((ext_vector_type(4))) u32 u32x4;

#define B_DIM 4
#define N_DIM 2048
#define C_DIM 1024
#define H_DIM 16
#define M_DIM (B_DIM * N_DIM)   // 8192
#define QSCALE 0.18033688011112042f   // log2(e)/8: folded into Q so attn P = exp2(S)

// 32x32x16 bf16 MFMA (gfx950-verified shape). Host pass must not see the
// amdgcn builtin -> stub it there (host never executes kernel bodies).
#if defined(__HIP_DEVICE_COMPILE__)
#define MFMA32(a, b, c) __builtin_amdgcn_mfma_f32_32x32x16_bf16(a, b, c, 0, 0, 0)
#define SETPRIO(n) __builtin_amdgcn_s_setprio(n)
#else
#define MFMA32(a, b, c) (c)
#define SETPRIO(n)
#endif

__device__ __forceinline__ u16 f2bf(float f) {
  u32 u = __builtin_bit_cast(u32, f);
  return (u16)((u + 0x7FFFu + ((u >> 16) & 1u)) >> 16);  // RNE
}

__device__ __forceinline__ void gload16(const void* g, void* l) {
  __builtin_amdgcn_global_load_lds(
      (const __attribute__((address_space(1))) u32*)g,
      (__attribute__((address_space(3))) u32*)l, 16, 0, 0);
}

// ------- merged prep: z=0..2 transpose+cast weights, z=3 cast x -> bf16 -------
// tcast: W[K][N] f32 -> Wt[N][K] bf16 (block 32x8, whole-block early-exit is
// uniform and precedes the barrier). cast: grid-stride float4 path.
__global__ void prep_kernel(const float* __restrict__ x, u16* __restrict__ xb,
                            const float* __restrict__ Wq, const float* __restrict__ Wkv,
                            const float* __restrict__ Wout,
                            u16* __restrict__ wqT, u16* __restrict__ wkvT,
                            u16* __restrict__ woT) {
  int tx = threadIdx.x, ty = threadIdx.y;  // block (32,8)
  if (blockIdx.z == 3) {                   // ---- cast x (2048 virtual blocks) ----
    int bid = blockIdx.y * 64 + blockIdx.x;
    int i = bid * 256 + ty * 32 + tx;
    const int n4 = M_DIM * C_DIM / 4;
    const int stride = 64 * 32 * 256;
    for (; i < n4; i += stride) {
      float4 v = ((const float4*)x)[i];
      ushort4 o;
      o.x = f2bf(v.x); o.y = f2bf(v.y); o.z = f2bf(v.z); o.w = f2bf(v.w);
      ((ushort4*)xb)[i] = o;
    }
    return;
  }
  const float* W; u16* Wt; int N;
  if (blockIdx.z == 0)      { W = Wq;   Wt = wqT;  N = C_DIM; }
  else if (blockIdx.z == 1) { W = Wkv;  Wt = wkvT; N = 2 * C_DIM; }
  else                      { W = Wout; Wt = woT;  N = C_DIM; }
  int n0 = blockIdx.x * 32, k0 = blockIdx.y * 32;
  if (n0 >= N) return;   // uniform across block
  __shared__ float tile[32][33];
  #pragma unroll
  for (int i = 0; i < 32; i += 8)
    tile[ty + i][tx] = W[(size_t)(k0 + ty + i) * N + (n0 + tx)];
  __syncthreads();
  #pragma unroll
  for (int i = 0; i < 32; i += 8)
    Wt[(size_t)(n0 + ty + i) * C_DIM + (k0 + tx)] = f2bf(tile[tx][ty + i]);
}

// ---------------- bf16 GEMM, m97 structure: C[M][N] = A[M][K] * Bt[N][K]^T ----------------
// MODE 1: f32 + bias.
// MODE 3: fused QKV (N=3072): cols 0..1023 -> q bf16 scaled by QSCALE (Cout);
//         1024..2047 -> kbuf bf16 (aux); 2048..3071 -> vt transposed
//         vt[(b*16+h)*64+d][n] bf16 (canonical token order).
template <int MODE>
__global__ __launch_bounds__(256) void gemm_bt_kernel(
    const u16* __restrict__ A, const u16* __restrict__ Bt, void* __restrict__ Cout,
    const float* __restrict__ bias, u16* __restrict__ vt, u16* __restrict__ aux,
    int K, int N) {
  __shared__ __align__(16) char lds[16384];  // A tile 128x32 bf16 @0, B tile @8192
  const int tid  = threadIdx.x;
  const int lane = tid & 63, w = tid >> 6;
  const int lr = lane & 15, g = lane >> 4;
  const int m0 = blockIdx.y * 128, n0 = blockIdx.x * 128;
  const int wm = w >> 1, wn = w & 1;

  f32x4 acc[4][4] = {};
  const int nkt = K >> 5;
  const int rsub = lane >> 2;   // 0..15
  const int csub = lane & 3;    // 0..3 (16B chunk within 64B row)
  for (int kt = 0; kt < nkt; ++kt) {
    #pragma unroll
    for (int j = 0; j < 2; ++j) {
      int rowblk = w * 2 + j;                 // wave-uniform
      int row = rowblk * 16 + rsub;
      gload16(A  + (size_t)(m0 + row) * K + kt * 32 + csub * 8, lds + rowblk * 1024);
      gload16(Bt + (size_t)(n0 + row) * K + kt * 32 + csub * 8, lds + 8192 + rowblk * 1024);
    }
    __syncthreads();
    bf16x8 a[4], b[4];
    #pragma unroll
    for (int m = 0; m < 4; ++m)
      a[m] = *(const bf16x8*)(lds + ((wm * 64 + m * 16 + lr) * 64 + g * 16));
    #pragma unroll
    for (int n = 0; n < 4; ++n)
      b[n] = *(const bf16x8*)(lds + 8192 + ((wn * 64 + n * 16 + lr) * 64 + g * 16));
    #pragma unroll
    for (int m = 0; m < 4; ++m)
      #pragma unroll
      for (int n = 0; n < 4; ++n)
        acc[m][n] = __builtin_amdgcn_mfma_f32_16x16x32_bf16(a[m], b[n], acc[m][n], 0, 0, 0);
    __syncthreads();
  }
  // epilogue: D layout col=lane&15, row=4*(lane>>4)+reg
  #pragma unroll
  for (int m = 0; m < 4; ++m) {
    #pragma unroll
    for (int n = 0; n < 4; ++n) {
      int col  = n0 + wn * 64 + n * 16 + lr;
      int row0 = m0 + wm * 64 + m * 16 + g * 4;
      if constexpr (MODE == 1) {
        #pragma unroll
        for (int r = 0; r < 4; ++r)
          ((float*)Cout)[(size_t)(row0 + r) * N + col] = acc[m][n][r] + bias[col];
      } else {
        // region is wave-uniform: boundaries are multiples of 64
        if (col < 1024) {           // Q, pre-scaled by QSCALE
          #pragma unroll
          for (int r = 0; r < 4; ++r)
            ((u16*)Cout)[(size_t)(row0 + r) * 1024 + col] = f2bf(acc[m][n][r] * QSCALE);
        } else if (col < 2048) {    // K
          int cc = col - 1024;
          #pragma unroll
          for (int r = 0; r < 4; ++r)
            aux[(size_t)(row0 + r) * 1024 + cc] = f2bf(acc[m][n][r]);
        } else {                    // V -> transposed vt[(b*16+h)*64+d][n]
          int cc = col - 2048;
          int hh = cc >> 6, d = cc & 63;
          int bb = row0 >> 11, nn = row0 & 2047;
          ushort4 pkv;
          pkv.x = f2bf(acc[m][n][0]); pkv.y = f2bf(acc[m][n][1]);
          pkv.z = f2bf(acc[m][n][2]); pkv.w = f2bf(acc[m][n][3]);
          *(ushort4*)(vt + ((size_t)(bb * 16 + hh) * 64 + d) * 2048 + nn) = pkv;
        }
      }
    }
  }
}

// ---------------- flash attention v8 (R10, verified) + T5 setprio ----------------
// block = 256 thr = 4 waves x 32 q-rows. KVB = 64. Q pre-scaled -> P = exp2(S).
// Swapped QK^T: st = mfma_32x32(K,Q) -> lane(q=l31,hi) reg r=t*8+j holds
// S^T[kv = 16t + phi(hi,j)][q], phi(hi,j) = 4hi+(j&3)+8*(j>>2). PV is invariant
// under kv-relabeling applied to BOTH A and B: A-frag word w =
// cvt_pk(e[2w],e[2w+1]) directly (no cross-lane), V^T B-frag = two ds_read_b64
// at kv = kb*16+4hi / kb*16+8+4hi (phi order). Row-sums via ones-MFMA.
// setprio(1) wraps the MFMA clusters (T5): 4 blocks/CU at different phases ->
// compute waves preempt other blocks' staging waves. Scheduler hint only.
// NOTE: 64q/wave doubling and single-b128 V reads both FAILED correctness
// (R9/R11/R12/R13) despite paper-correct derivations -- do not retry blind.
__global__ __launch_bounds__(256) void attn_kernel(
    const u16* __restrict__ Qb, const u16* __restrict__ Kb,
    const u16* __restrict__ Vt, u16* __restrict__ AO) {
  __shared__ __align__(16) char lds[32768];
  const int tid  = threadIdx.x;
  const int lane = tid & 63, w = tid >> 6;
  const int l31 = lane & 31, hi = lane >> 5;
  const int lin = blockIdx.x;
  const int nid = (lin & 7) * 128 + (lin >> 3);   // XCD swizzle: (b,h) colocated
  const int bh = nid >> 4;
  const int b = bh >> 4, h = bh & 15;
  const int q0 = (nid & 15) * 128 + w * 32;
  const size_t rowbase = (size_t)b * N_DIM;

  // Q fragments (B-frag: col=q=l31, k=d_local=8*hi+j), dk = 16-d block
  bf16x8 qf[4];
  #pragma unroll
  for (int dk = 0; dk < 4; ++dk)
    qf[dk] = *(const bf16x8*)(Qb + (rowbase + q0 + l31) * C_DIM + h * 64 + dk * 16 + hi * 8);

  bf16x8 ones8;
  #pragma unroll
  for (int j = 0; j < 8; ++j) ones8[j] = (short)0x3F80;  // bf16 1.0

  f32x16 accO[2] = {};   // [d 32-block]
  f32x16 accSum = {};

  auto STAGE = [&](int kt, int buf) {
    #pragma unroll
    for (int j = 0; j < 2; ++j) {
      int c = (w * 2 + j) * 64 + lane;              // 16B-chunk id 0..511
      int row = c >> 3, slot = (c & 7) ^ (row & 7); // source pre-swizzle (involution)
      gload16(Kb + (size_t)(rowbase + kt * 64 + row) * 1024 + h * 64 + slot * 8,
              lds + buf * 8192 + (w * 2 + j) * 1024);
      gload16(Vt + ((size_t)bh * 64 + row) * 2048 + kt * 64 + slot * 8,
              lds + 16384 + buf * 8192 + (w * 2 + j) * 1024);
    }
  };

  STAGE(0, 0);
  __syncthreads();   // drains vmcnt(0): tile 0 staged

  for (int kt = 0; kt < N_DIM / 64; ++kt) {
    if (kt + 1 < N_DIM / 64) STAGE(kt + 1, (kt + 1) & 1);  // prefetch, drained by end barrier
    const char* K_ = lds + (kt & 1) * 8192;
    const char* V_ = lds + 16384 + (kt & 1) * 8192;

    u32 paw[4][4];   // [kv 16-block][A-frag word]; all indices compile-time
    #pragma unroll
    for (int kvb = 0; kvb < 2; ++kvb) {
      // ---- S^T (32 kv x 32 q) = K Q^T over d=64 (4 chained MFMA) ----
      SETPRIO(1);
      f32x16 st = {};
      #pragma unroll
      for (int dk = 0; dk < 4; ++dk) {
        bf16x8 kf_ = *(const bf16x8*)(K_ + (kvb * 32 + l31) * 128 + (((2 * dk + hi) ^ (l31 & 7)) << 4));
        st = MFMA32(kf_, qf[dk], st);
      }
      SETPRIO(0);
      // ---- P = exp2(S); direct pack: word w = {e[2w], e[2w+1]} ----
      #pragma unroll
      for (int t = 0; t < 2; ++t) {
        float e[8];
        #pragma unroll
        for (int j = 0; j < 8; ++j) e[j] = __builtin_amdgcn_exp2f(st[t * 8 + j]);
        #pragma unroll
        for (int ww = 0; ww < 4; ++ww) {
          u32 r_;
          asm("v_cvt_pk_bf16_f32 %0, %1, %2" : "=v"(r_) : "v"(e[2 * ww]), "v"(e[2 * ww + 1]));
          paw[kvb * 2 + t][ww] = r_;
        }
      }
    }

    // ---- O += P V; B-frag reads match phi: kv = kb*16+4hi+(0..3), +8 ----
    SETPRIO(1);
    #pragma unroll
    for (int kb = 0; kb < 4; ++kb) {
      u32x4 pk4 = {paw[kb][0], paw[kb][1], paw[kb][2], paw[kb][3]};
      bf16x8 pab = __builtin_bit_cast(bf16x8, pk4);
      accSum = MFMA32(pab, ones8, accSum);
      #pragma unroll
      for (int db = 0; db < 2; ++db) {
        const char* vrow = V_ + (db * 32 + l31) * 128;
        int sw = l31 & 7;
        uint2 v0 = *(const uint2*)(vrow + (((2 * kb) ^ sw) << 4) + 8 * hi);       // kv kb*16+4hi..+3
        uint2 v1 = *(const uint2*)(vrow + (((2 * kb + 1) ^ sw) << 4) + 8 * hi);   // kv kb*16+8+4hi..+3
        u32x4 vv = {v0.x, v0.y, v1.x, v1.y};
        bf16x8 vf_ = __builtin_bit_cast(bf16x8, vv);
        accO[db] = MFMA32(pab, vf_, accO[db]);
      }
    }
    SETPRIO(0);
    __syncthreads();  // drains prefetch vmcnt + releases buffers
  }

  // ---- epilogue: D row map = (r&3)+8*(r>>2)+4*hi (m74/m101) ----
  #pragma unroll
  for (int r = 0; r < 16; ++r) {
    int qrow = q0 + (r & 3) + 8 * (r >> 2) + 4 * hi;
    float inv = __builtin_amdgcn_rcpf(accSum[r]);
    #pragma unroll
    for (int db = 0; db < 2; ++db)
      AO[(rowbase + qrow) * C_DIM + h * 64 + db * 32 + l31] = f2bf(accO[db][r] * inv);
  }
}

extern "C" void kernel_launch(void* const* d_in, const int* in_sizes, int n_in,
                              void* d_out, int out_size, void* d_ws, size_t ws_size,
                              hipStream_t stream) {
  (void)in_sizes; (void)n_in; (void)out_size; (void)ws_size;
  const float* x    = (const float*)d_in[0];
  const float* Wq   = (const float*)d_in[1];
  const float* Wkv  = (const float*)d_in[2];
  const float* Wout = (const float*)d_in[3];
  const float* bout = (const float*)d_in[4];
  float* out = (float*)d_out;

  // workspace layout (72 MiB)
  char* ws = (char*)d_ws;
  u16* xb   = (u16*)(ws);                       // 16 MiB: x bf16; reused as attn-out
  u16* wqT  = (u16*)(ws + (16u << 20));         //  2 MiB  \ contiguous: [Wq^T; Wkv^T]
  u16* wkvT = (u16*)(ws + (18u << 20));         //  4 MiB  /  = 3072 rows x 1024 k
  u16* woT  = (u16*)(ws + (22u << 20));         //  2 MiB
  u16* q    = (u16*)(ws + (24u << 20));         // 16 MiB  (pre-scaled by QSCALE)
  u16* kbuf = (u16*)(ws + (40u << 20));         // 16 MiB  [8192][1024] bf16
  u16* vT   = (u16*)(ws + (56u << 20));         // 16 MiB  [4096 d-rows][2048] bf16
  u16* ao   = xb;                               // alias: x dead after QKV gemm

  // one prep launch: x-cast (z=3) + all three weight transposes (z=0..2)
  prep_kernel<<<dim3(2 * C_DIM / 32, C_DIM / 32, 4), dim3(32, 8), 0, stream>>>(
      x, xb, Wq, Wkv, Wout, wqT, wkvT, woT);

  // fused QKV projection: Bt = [Wq^T; Wkv^T] (contiguous), N = 3072
  gemm_bt_kernel<3><<<dim3(3 * C_DIM / 128, M_DIM / 128), 256, 0, stream>>>(
      xb, wqT, q, nullptr, vT, kbuf, C_DIM, 3 * C_DIM);

  attn_kernel<<<dim3(N_DIM / 128 * B_DIM * H_DIM), 256, 0, stream>>>(q, kbuf, vT, ao);

  gemm_bt_kernel<1><<<dim3(C_DIM / 128, M_DIM / 128), 256, 0, stream>>>(
      ao, woT, out, bout, nullptr, nullptr, C_DIM, C_DIM);
}

// Round 16
// 214.462 us; speedup vs baseline: 1.0494x; 1.0494x over previous
//
#include <hip/hip_runtime.h>
#include <stdint.h>

typedef unsigned short u16;
typedef unsigned int u32;
typedef __attribute__((ext_vector_type(8))) short bf16x8;      // 8 bf16 (4 VGPRs) MFMA A/B frag
typedef __attribute__((ext_vector_type(4))) float f32x4;       // 16x16 MFMA C/D frag
typedef __attribute__((ext_vector_type(16))) float f32x16;     // 32x32 MFMA C/D frag
typedef __attribute__((ext_vector_type(4))) u32 u32x4;

#define B_DIM 4
#define N_DIM 2048
#define C_DIM 1024
#define H_DIM 16
#define M_DIM (B_DIM * N_DIM)   // 8192
#define QSCALE 0.18033688011112042f   // log2(e)/8: folded into Q so attn P = exp2(S)

// 32x32x16 bf16 MFMA (gfx950-verified shape). Host pass must not see the
// amdgcn builtin -> stub it there (host never executes kernel bodies).
#if defined(__HIP_DEVICE_COMPILE__)
#define MFMA32(a, b, c) __builtin_amdgcn_mfma_f32_32x32x16_bf16(a, b, c, 0, 0, 0)
#else
#define MFMA32(a, b, c) (c)
#endif

__device__ __forceinline__ u16 f2bf(float f) {
  u32 u = __builtin_bit_cast(u32, f);
  return (u16)((u + 0x7FFFu + ((u >> 16) & 1u)) >> 16);  // RNE
}

__device__ __forceinline__ void gload16(const void* g, void* l) {
  __builtin_amdgcn_global_load_lds(
      (const __attribute__((address_space(1))) u32*)g,
      (__attribute__((address_space(3))) u32*)l, 16, 0, 0);
}

// ------- merged prep: z=0..2 transpose+cast weights, z=3 cast x -> bf16 -------
__global__ void prep_kernel(const float* __restrict__ x, u16* __restrict__ xb,
                            const float* __restrict__ Wq, const float* __restrict__ Wkv,
                            const float* __restrict__ Wout,
                            u16* __restrict__ wqT, u16* __restrict__ wkvT,
                            u16* __restrict__ woT) {
  int tx = threadIdx.x, ty = threadIdx.y;  // block (32,8)
  if (blockIdx.z == 3) {                   // ---- cast x (2048 virtual blocks) ----
    int bid = blockIdx.y * 64 + blockIdx.x;
    int i = bid * 256 + ty * 32 + tx;
    const int n4 = M_DIM * C_DIM / 4;
    const int stride = 64 * 32 * 256;
    for (; i < n4; i += stride) {
      float4 v = ((const float4*)x)[i];
      ushort4 o;
      o.x = f2bf(v.x); o.y = f2bf(v.y); o.z = f2bf(v.z); o.w = f2bf(v.w);
      ((ushort4*)xb)[i] = o;
    }
    return;
  }
  const float* W; u16* Wt; int N;
  if (blockIdx.z == 0)      { W = Wq;   Wt = wqT;  N = C_DIM; }
  else if (blockIdx.z == 1) { W = Wkv;  Wt = wkvT; N = 2 * C_DIM; }
  else                      { W = Wout; Wt = woT;  N = C_DIM; }
  int n0 = blockIdx.x * 32, k0 = blockIdx.y * 32;
  if (n0 >= N) return;   // uniform across block
  __shared__ float tile[32][33];
  #pragma unroll
  for (int i = 0; i < 32; i += 8)
    tile[ty + i][tx] = W[(size_t)(k0 + ty + i) * N + (n0 + tx)];
  __syncthreads();
  #pragma unroll
  for (int i = 0; i < 32; i += 8)
    Wt[(size_t)(n0 + ty + i) * C_DIM + (k0 + tx)] = f2bf(tile[tx][ty + i]);
}

// ---------------- bf16 GEMM, m97 structure: C[M][N] = A[M][K] * Bt[N][K]^T ----------------
// MODE 1: f32 + bias.
// MODE 3: fused QKV (N=3072): cols 0..1023 -> q bf16 scaled by QSCALE (Cout);
//         1024..2047 -> kbuf bf16 (aux); 2048..3071 -> vt transposed
//         vt[(b*16+h)*64+d][n] bf16 (canonical token order).
template <int MODE>
__global__ __launch_bounds__(256) void gemm_bt_kernel(
    const u16* __restrict__ A, const u16* __restrict__ Bt, void* __restrict__ Cout,
    const float* __restrict__ bias, u16* __restrict__ vt, u16* __restrict__ aux,
    int K, int N) {
  __shared__ __align__(16) char lds[16384];  // A tile 128x32 bf16 @0, B tile @8192
  const int tid  = threadIdx.x;
  const int lane = tid & 63, w = tid >> 6;
  const int lr = lane & 15, g = lane >> 4;
  const int m0 = blockIdx.y * 128, n0 = blockIdx.x * 128;
  const int wm = w >> 1, wn = w & 1;

  f32x4 acc[4][4] = {};
  const int nkt = K >> 5;
  const int rsub = lane >> 2;   // 0..15
  const int csub = lane & 3;    // 0..3 (16B chunk within 64B row)
  for (int kt = 0; kt < nkt; ++kt) {
    #pragma unroll
    for (int j = 0; j < 2; ++j) {
      int rowblk = w * 2 + j;                 // wave-uniform
      int row = rowblk * 16 + rsub;
      gload16(A  + (size_t)(m0 + row) * K + kt * 32 + csub * 8, lds + rowblk * 1024);
      gload16(Bt + (size_t)(n0 + row) * K + kt * 32 + csub * 8, lds + 8192 + rowblk * 1024);
    }
    __syncthreads();
    bf16x8 a[4], b[4];
    #pragma unroll
    for (int m = 0; m < 4; ++m)
      a[m] = *(const bf16x8*)(lds + ((wm * 64 + m * 16 + lr) * 64 + g * 16));
    #pragma unroll
    for (int n = 0; n < 4; ++n)
      b[n] = *(const bf16x8*)(lds + 8192 + ((wn * 64 + n * 16 + lr) * 64 + g * 16));
    #pragma unroll
    for (int m = 0; m < 4; ++m)
      #pragma unroll
      for (int n = 0; n < 4; ++n)
        acc[m][n] = __builtin_amdgcn_mfma_f32_16x16x32_bf16(a[m], b[n], acc[m][n], 0, 0, 0);
    __syncthreads();
  }
  // epilogue: D layout col=lane&15, row=4*(lane>>4)+reg
  #pragma unroll
  for (int m = 0; m < 4; ++m) {
    #pragma unroll
    for (int n = 0; n < 4; ++n) {
      int col  = n0 + wn * 64 + n * 16 + lr;
      int row0 = m0 + wm * 64 + m * 16 + g * 4;
      if constexpr (MODE == 1) {
        #pragma unroll
        for (int r = 0; r < 4; ++r)
          ((float*)Cout)[(size_t)(row0 + r) * N + col] = acc[m][n][r] + bias[col];
      } else {
        // region is wave-uniform: boundaries are multiples of 64
        if (col < 1024) {           // Q, pre-scaled by QSCALE
          #pragma unroll
          for (int r = 0; r < 4; ++r)
            ((u16*)Cout)[(size_t)(row0 + r) * 1024 + col] = f2bf(acc[m][n][r] * QSCALE);
        } else if (col < 2048) {    // K
          int cc = col - 1024;
          #pragma unroll
          for (int r = 0; r < 4; ++r)
            aux[(size_t)(row0 + r) * 1024 + cc] = f2bf(acc[m][n][r]);
        } else {                    // V -> transposed vt[(b*16+h)*64+d][n]
          int cc = col - 2048;
          int hh = cc >> 6, d = cc & 63;
          int bb = row0 >> 11, nn = row0 & 2047;
          ushort4 pkv;
          pkv.x = f2bf(acc[m][n][0]); pkv.y = f2bf(acc[m][n][1]);
          pkv.z = f2bf(acc[m][n][2]); pkv.w = f2bf(acc[m][n][3]);
          *(ushort4*)(vt + ((size_t)(bb * 16 + hh) * 64 + d) * 2048 + nn) = pkv;
        }
      }
    }
  }
}

// ---------------- flash attention v8 (R10/R14, verified; setprio REVERTED) ----------------
// block = 256 thr = 4 waves x 32 q-rows. KVB = 64. Q pre-scaled -> P = exp2(S).
// Swapped QK^T: st = mfma_32x32(K,Q) -> lane(q=l31,hi) reg r=t*8+j holds
// S^T[kv = 16t + phi(hi,j)][q], phi(hi,j) = 4hi+(j&3)+8*(j>>2). PV is invariant
// under kv-relabeling applied to BOTH A and B: A-frag word w =
// cvt_pk(e[2w],e[2w+1]) directly (no cross-lane), V^T B-frag = two ds_read_b64
// at kv = kb*16+4hi / kb*16+8+4hi (phi order). Row-sums via ones-MFMA.
// NOTE: setprio (R15) measured -4% here -> removed. 64q/wave doubling and
// single-b128 V reads FAILED correctness (R9/R11/R12/R13) -- do not retry blind.
__global__ __launch_bounds__(256) void attn_kernel(
    const u16* __restrict__ Qb, const u16* __restrict__ Kb,
    const u16* __restrict__ Vt, u16* __restrict__ AO) {
  __shared__ __align__(16) char lds[32768];
  const int tid  = threadIdx.x;
  const int lane = tid & 63, w = tid >> 6;
  const int l31 = lane & 31, hi = lane >> 5;
  const int lin = blockIdx.x;
  const int nid = (lin & 7) * 128 + (lin >> 3);   // XCD swizzle: (b,h) colocated
  const int bh = nid >> 4;
  const int b = bh >> 4, h = bh & 15;
  const int q0 = (nid & 15) * 128 + w * 32;
  const size_t rowbase = (size_t)b * N_DIM;

  // Q fragments (B-frag: col=q=l31, k=d_local=8*hi+j), dk = 16-d block
  bf16x8 qf[4];
  #pragma unroll
  for (int dk = 0; dk < 4; ++dk)
    qf[dk] = *(const bf16x8*)(Qb + (rowbase + q0 + l31) * C_DIM + h * 64 + dk * 16 + hi * 8);

  bf16x8 ones8;
  #pragma unroll
  for (int j = 0; j < 8; ++j) ones8[j] = (short)0x3F80;  // bf16 1.0

  f32x16 accO[2] = {};   // [d 32-block]
  f32x16 accSum = {};

  auto STAGE = [&](int kt, int buf) {
    #pragma unroll
    for (int j = 0; j < 2; ++j) {
      int c = (w * 2 + j) * 64 + lane;              // 16B-chunk id 0..511
      int row = c >> 3, slot = (c & 7) ^ (row & 7); // source pre-swizzle (involution)
      gload16(Kb + (size_t)(rowbase + kt * 64 + row) * 1024 + h * 64 + slot * 8,
              lds + buf * 8192 + (w * 2 + j) * 1024);
      gload16(Vt + ((size_t)bh * 64 + row) * 2048 + kt * 64 + slot * 8,
              lds + 16384 + buf * 8192 + (w * 2 + j) * 1024);
    }
  };

  STAGE(0, 0);
  __syncthreads();   // drains vmcnt(0): tile 0 staged

  for (int kt = 0; kt < N_DIM / 64; ++kt) {
    if (kt + 1 < N_DIM / 64) STAGE(kt + 1, (kt + 1) & 1);  // prefetch, drained by end barrier
    const char* K_ = lds + (kt & 1) * 8192;
    const char* V_ = lds + 16384 + (kt & 1) * 8192;

    u32 paw[4][4];   // [kv 16-block][A-frag word]; all indices compile-time
    #pragma unroll
    for (int kvb = 0; kvb < 2; ++kvb) {
      // ---- S^T (32 kv x 32 q) = K Q^T over d=64 (4 chained MFMA) ----
      f32x16 st = {};
      #pragma unroll
      for (int dk = 0; dk < 4; ++dk) {
        bf16x8 kf_ = *(const bf16x8*)(K_ + (kvb * 32 + l31) * 128 + (((2 * dk + hi) ^ (l31 & 7)) << 4));
        st = MFMA32(kf_, qf[dk], st);
      }
      // ---- P = exp2(S); direct pack: word w = {e[2w], e[2w+1]} ----
      #pragma unroll
      for (int t = 0; t < 2; ++t) {
        float e[8];
        #pragma unroll
        for (int j = 0; j < 8; ++j) e[j] = __builtin_amdgcn_exp2f(st[t * 8 + j]);
        #pragma unroll
        for (int ww = 0; ww < 4; ++ww) {
          u32 r_;
          asm("v_cvt_pk_bf16_f32 %0, %1, %2" : "=v"(r_) : "v"(e[2 * ww]), "v"(e[2 * ww + 1]));
          paw[kvb * 2 + t][ww] = r_;
        }
      }
    }

    // ---- O += P V; B-frag reads match phi: kv = kb*16+4hi+(0..3), +8 ----
    #pragma unroll
    for (int kb = 0; kb < 4; ++kb) {
      u32x4 pk4 = {paw[kb][0], paw[kb][1], paw[kb][2], paw[kb][3]};
      bf16x8 pab = __builtin_bit_cast(bf16x8, pk4);
      accSum = MFMA32(pab, ones8, accSum);
      #pragma unroll
      for (int db = 0; db < 2; ++db) {
        const char* vrow = V_ + (db * 32 + l31) * 128;
        int sw = l31 & 7;
        uint2 v0 = *(const uint2*)(vrow + (((2 * kb) ^ sw) << 4) + 8 * hi);       // kv kb*16+4hi..+3
        uint2 v1 = *(const uint2*)(vrow + (((2 * kb + 1) ^ sw) << 4) + 8 * hi);   // kv kb*16+8+4hi..+3
        u32x4 vv = {v0.x, v0.y, v1.x, v1.y};
        bf16x8 vf_ = __builtin_bit_cast(bf16x8, vv);
        accO[db] = MFMA32(pab, vf_, accO[db]);
      }
    }
    __syncthreads();  // drains prefetch vmcnt + releases buffers
  }

  // ---- epilogue: D row map = (r&3)+8*(r>>2)+4*hi (m74/m101) ----
  #pragma unroll
  for (int r = 0; r < 16; ++r) {
    int qrow = q0 + (r & 3) + 8 * (r >> 2) + 4 * hi;
    float inv = __builtin_amdgcn_rcpf(accSum[r]);
    #pragma unroll
    for (int db = 0; db < 2; ++db)
      AO[(rowbase + qrow) * C_DIM + h * 64 + db * 32 + l31] = f2bf(accO[db][r] * inv);
  }
}

extern "C" void kernel_launch(void* const* d_in, const int* in_sizes, int n_in,
                              void* d_out, int out_size, void* d_ws, size_t ws_size,
                              hipStream_t stream) {
  (void)in_sizes; (void)n_in; (void)out_size; (void)ws_size;
  const float* x    = (const float*)d_in[0];
  const float* Wq   = (const float*)d_in[1];
  const float* Wkv  = (const float*)d_in[2];
  const float* Wout = (const float*)d_in[3];
  const float* bout = (const float*)d_in[4];
  float* out = (float*)d_out;

  // workspace layout (72 MiB)
  char* ws = (char*)d_ws;
  u16* xb   = (u16*)(ws);                       // 16 MiB: x bf16; reused as attn-out
  u16* wqT  = (u16*)(ws + (16u << 20));         //  2 MiB  \ contiguous: [Wq^T; Wkv^T]
  u16* wkvT = (u16*)(ws + (18u << 20));         //  4 MiB  /  = 3072 rows x 1024 k
  u16* woT  = (u16*)(ws + (22u << 20));         //  2 MiB
  u16* q    = (u16*)(ws + (24u << 20));         // 16 MiB  (pre-scaled by QSCALE)
  u16* kbuf = (u16*)(ws + (40u << 20));         // 16 MiB  [8192][1024] bf16
  u16* vT   = (u16*)(ws + (56u << 20));         // 16 MiB  [4096 d-rows][2048] bf16
  u16* ao   = xb;                               // alias: x dead after QKV gemm

  // one prep launch: x-cast (z=3) + all three weight transposes (z=0..2)
  prep_kernel<<<dim3(2 * C_DIM / 32, C_DIM / 32, 4), dim3(32, 8), 0, stream>>>(
      x, xb, Wq, Wkv, Wout, wqT, wkvT, woT);

  // fused QKV projection: Bt = [Wq^T; Wkv^T] (contiguous), N = 3072
  gemm_bt_kernel<3><<<dim3(3 * C_DIM / 128, M_DIM / 128), 256, 0, stream>>>(
      xb, wqT, q, nullptr, vT, kbuf, C_DIM, 3 * C_DIM);

  attn_kernel<<<dim3(N_DIM / 128 * B_DIM * H_DIM), 256, 0, stream>>>(q, kbuf, vT, ao);

  gemm_bt_kernel<1><<<dim3(C_DIM / 128, M_DIM / 128), 256, 0, stream>>>(
      ao, woT, out, bout, nullptr, nullptr, C_DIM, C_DIM);
}